// Round 1
// baseline (2708.660 us; speedup 1.0000x reference)
//
#include <hip/hip_runtime.h>
#include <hip/hip_bf16.h>

#define M 8192
#define N 16384
#define K 768
#define TOPK 64

typedef float f32x4 __attribute__((ext_vector_type(4)));
typedef short s16x8 __attribute__((ext_vector_type(8)));
typedef short s16x4 __attribute__((ext_vector_type(4)));

__device__ __forceinline__ unsigned short f2bf(float f) {
    unsigned int u = __float_as_uint(f);
    unsigned int r = (u + 0x7FFFu + ((u >> 16) & 1u)) >> 16;
    return (unsigned short)r;
}
__device__ __forceinline__ float bf2f(unsigned short s) {
    return __uint_as_float(((unsigned int)s) << 16);
}

// ---------------------------------------------------------------------------
// K1: pre_codes = x @ W^T + b   (bf16 MFMA, fp32 out)
// 128x128 tile, BK=64, 256 threads (4 waves, 2x2), XOR-swizzled LDS.
// ---------------------------------------------------------------------------
#define BM 128
#define BN 128
#define BK 64

__global__ __launch_bounds__(256, 2)
void gemm_kernel(const float* __restrict__ x, const float* __restrict__ W,
                 const float* __restrict__ b, float* __restrict__ pre) {
    __shared__ __align__(16) unsigned short As[BM * BK];  // 16 KB, row-major, 8x16B chunks/row, chunk^=(row&7)
    __shared__ __align__(16) unsigned short Bs[BN * BK];

    const int tid = threadIdx.x;
    const int bm = blockIdx.x & 63;          // M/BM = 64  (consecutive blocks share bn -> W panel L2 reuse)
    const int bn = blockIdx.x >> 6;          // N/BN = 128
    const int wave = tid >> 6, lane = tid & 63;
    const int wr = (wave >> 1) * 64, wc = (wave & 1) * 64;
    const int lrow = lane & 15, lk = lane >> 4;

    f32x4 acc[4][4];
    #pragma unroll
    for (int i = 0; i < 4; ++i)
        #pragma unroll
        for (int j = 0; j < 4; ++j) acc[i][j] = (f32x4){0.f, 0.f, 0.f, 0.f};

    // staging: thread -> row tid>>1 (0..127), 32 cols at (tid&1)*32
    const int sr = tid >> 1;
    const int scol = (tid & 1) * 32;
    const float* xp = x + (size_t)(bm * BM + sr) * K + scol;
    const float* wp = W + (size_t)(bn * BN + sr) * K + scol;
    s16x8* Asv = (s16x8*)As;
    s16x8* Bsv = (s16x8*)Bs;

    for (int kt = 0; kt < K; kt += BK) {
        const float4* xv = (const float4*)(xp + kt);
        const float4* wv = (const float4*)(wp + kt);
        #pragma unroll
        for (int q = 0; q < 4; ++q) {
            float4 v0 = xv[2 * q], v1 = xv[2 * q + 1];
            s16x8 t;
            t[0] = f2bf(v0.x); t[1] = f2bf(v0.y); t[2] = f2bf(v0.z); t[3] = f2bf(v0.w);
            t[4] = f2bf(v1.x); t[5] = f2bf(v1.y); t[6] = f2bf(v1.z); t[7] = f2bf(v1.w);
            int chunk = (((tid & 1) * 4 + q) ^ (sr & 7));
            Asv[sr * 8 + chunk] = t;
        }
        #pragma unroll
        for (int q = 0; q < 4; ++q) {
            float4 v0 = wv[2 * q], v1 = wv[2 * q + 1];
            s16x8 t;
            t[0] = f2bf(v0.x); t[1] = f2bf(v0.y); t[2] = f2bf(v0.z); t[3] = f2bf(v0.w);
            t[4] = f2bf(v1.x); t[5] = f2bf(v1.y); t[6] = f2bf(v1.z); t[7] = f2bf(v1.w);
            int chunk = (((tid & 1) * 4 + q) ^ (sr & 7));
            Bsv[sr * 8 + chunk] = t;
        }
        __syncthreads();
        #pragma unroll
        for (int kk = 0; kk < 2; ++kk) {
            s16x8 af[4], bfr[4];
            #pragma unroll
            for (int i = 0; i < 4; ++i) {
                int ar = wr + i * 16 + lrow;
                af[i] = Asv[ar * 8 + ((kk * 4 + lk) ^ (ar & 7))];
                int br = wc + i * 16 + lrow;
                bfr[i] = Bsv[br * 8 + ((kk * 4 + lk) ^ (br & 7))];
            }
            #pragma unroll
            for (int i = 0; i < 4; ++i)
                #pragma unroll
                for (int j = 0; j < 4; ++j)
                    acc[i][j] = __builtin_amdgcn_mfma_f32_16x16x32_bf16(af[i], bfr[j], acc[i][j], 0, 0, 0);
        }
        __syncthreads();
    }

    // epilogue: C row = (lane>>4)*4 + reg, col = lane&15  (m89-verified layout)
    const int row0 = bm * BM + wr + (lane >> 4) * 4;
    const int col0 = bn * BN + wc + lrow;
    #pragma unroll
    for (int j = 0; j < 4; ++j) {
        float bias = b[col0 + j * 16];
        #pragma unroll
        for (int i = 0; i < 4; ++i) {
            #pragma unroll
            for (int rg = 0; rg < 4; ++rg) {
                pre[(size_t)(row0 + i * 16 + rg) * N + (col0 + j * 16)] = acc[i][j][rg] + bias;
            }
        }
    }
}

// ---------------------------------------------------------------------------
// K2: per-row top-64 select (with fp64 boundary-band recompute) + codes row
//     write + fused sparse decode.  One 256-thread block per row.
// ---------------------------------------------------------------------------
__global__ __launch_bounds__(256, 2)
void select_kernel(const float* __restrict__ pre, const float* __restrict__ x,
                   const float* __restrict__ W, const float* __restrict__ b,
                   const float* __restrict__ D,
                   float* __restrict__ recon, float* __restrict__ codes) {
    __shared__ __align__(16) unsigned short rowv[N];   // 32 KB bf16 copy of the row
    __shared__ int hist[256];                          // linear bins over (3.0, 7.0)
    __shared__ float xrow[K];
    __shared__ double prec[128];
    __shared__ int   band_i[128];
    __shared__ int   sure_i[64];
    __shared__ float sure_v[64];
    __shared__ int   fidx[64];
    __shared__ float fval[64];
    __shared__ unsigned int bitmap[N / 32];            // 2 KB
    __shared__ int cnt_sure, cnt_band, sel_cnt, binB;

    const int r = blockIdx.x;
    const int tid = threadIdx.x;
    const float* prow = pre + (size_t)r * N;

    // init
    hist[tid] = 0;
    if (tid < 64) { fidx[tid] = -1; fval[tid] = 0.f; }
    for (int i = tid; i < N / 32; i += 256) bitmap[i] = 0u;
    if (tid == 0) { cnt_sure = 0; cnt_band = 0; sel_cnt = 0; binB = 0; }
    __syncthreads();

    // 1. load row (float4), stash bf16 in LDS, histogram values > 3.0
    for (int it = 0; it < 16; ++it) {
        int i4 = (it * 256 + tid) * 4;
        float4 v = *(const float4*)(prow + i4);
        s16x4 t;
        t[0] = (short)f2bf(v.x); t[1] = (short)f2bf(v.y);
        t[2] = (short)f2bf(v.z); t[3] = (short)f2bf(v.w);
        ((s16x4*)rowv)[it * 256 + tid] = t;
        float vv[4] = {v.x, v.y, v.z, v.w};
        #pragma unroll
        for (int c = 0; c < 4; ++c) {
            if (vv[c] > 3.0f) {
                int bi = (int)((vv[c] - 3.0f) * 64.0f);
                if (bi > 255) bi = 255;
                atomicAdd(&hist[bi], 1);
            }
        }
    }
    __syncthreads();

    // 2. find bin containing approx rank-64 value A (suffix scan from top)
    if (tid == 0) {
        int c = 0, B = 0;
        for (int bi = 255; bi >= 0; --bi) { c += hist[bi]; if (c >= 64) { B = bi; break; } }
        binB = B;
    }
    __syncthreads();
    const float edge = 3.0f + binB * 0.015625f;
    const float hi = edge + 0.015625f + 0.10f;   // above: surely in true top-64
    const float lo = edge - 0.015625f - 0.10f;   // below: surely out

    // 3. compact sure / band lists (compare on bf16 values; margins absorb rounding)
    for (int i = tid; i < N; i += 256) {
        float v = bf2f(rowv[i]);
        if (v >= hi) {
            int p = atomicAdd(&cnt_sure, 1);
            if (p < 64) { sure_i[p] = i; sure_v[p] = prow[i]; }   // store fp32 value
        } else if (v >= lo) {
            int p = atomicAdd(&cnt_band, 1);
            if (p < 128) { band_i[p] = i; }
        }
    }
    // 4. load x row
    for (int i = tid; i < K; i += 256) xrow[i] = x[(size_t)r * K + i];
    __syncthreads();

    const int nsure = min(cnt_sure, 64);
    const int nband = min(cnt_band, 128);
    int need = TOPK - nsure;
    if (need < 0) need = 0;

    // 5. fp64 recompute of band candidates (one wave per candidate)
    const int wv = tid >> 6, lane = tid & 63;
    for (int c = wv; c < nband; c += 4) {
        const float* wrp = W + (size_t)band_i[c] * K;
        double s = 0.0;
        #pragma unroll
        for (int j = 0; j < 12; ++j) {
            int d = lane + 64 * j;
            s += (double)xrow[d] * (double)wrp[d];
        }
        #pragma unroll
        for (int off = 32; off >= 1; off >>= 1) s += __shfl_xor(s, off, 64);
        if (lane == 0) prec[c] = s + (double)b[band_i[c]];
    }
    __syncthreads();

    // 6. exact rank within band (tie-break by index); select `need`
    for (int c = tid; c < nband; c += 256) {
        double pc = prec[c];
        int ic = band_i[c];
        int rank = 0;
        for (int j = 0; j < nband; ++j) {
            double pj = prec[j];
            if (pj > pc || (pj == pc && band_i[j] < ic)) ++rank;
        }
        if (rank < need) {
            int p = atomicAdd(&sel_cnt, 1);
            int slot = nsure + p;
            if (slot < 64) { fidx[slot] = ic; fval[slot] = (float)pc; }
        }
    }
    if (tid < nsure) { fidx[tid] = sure_i[tid]; fval[tid] = sure_v[tid]; }
    __syncthreads();

    // 7. bitmap of selected features
    if (tid < 64 && fidx[tid] >= 0)
        atomicOr(&bitmap[fidx[tid] >> 5], 1u << (fidx[tid] & 31));
    __syncthreads();

    // 8. write full codes row (zeros + 64 values), float4 stores
    float* crow = codes + (size_t)r * N;
    for (int it = 0; it < 16; ++it) {
        int i4 = (it * 256 + tid) * 4;
        float4 v = {0.f, 0.f, 0.f, 0.f};
        unsigned int mw = bitmap[i4 >> 5];
        if ((mw >> (i4 & 31)) & 0xFu) {
            float* pv = (float*)&v;
            #pragma unroll
            for (int c = 0; c < 4; ++c) {
                if ((mw >> ((i4 & 31) + c)) & 1u) {
                    int idx = i4 + c;
                    for (int t = 0; t < 64; ++t)
                        if (fidx[t] == idx) pv[c] = fval[t];
                }
            }
        }
        *(float4*)(crow + i4) = v;
    }

    // 9. fused sparse decode: recon[r, :] = sum_k fval[k] * D[fidx[k], :]
    float a0 = 0.f, a1 = 0.f, a2 = 0.f;
    for (int t = 0; t < 64; ++t) {
        int f = fidx[t];
        if (f < 0) continue;
        float v = fval[t];
        const float* dr = D + (size_t)f * K;
        a0 += v * dr[tid];
        a1 += v * dr[tid + 256];
        a2 += v * dr[tid + 512];
    }
    float* rr = recon + (size_t)r * K;
    rr[tid] = a0; rr[tid + 256] = a1; rr[tid + 512] = a2;
}

// ---------------------------------------------------------------------------
extern "C" void kernel_launch(void* const* d_in, const int* in_sizes, int n_in,
                              void* d_out, int out_size, void* d_ws, size_t ws_size,
                              hipStream_t stream) {
    const float* x = (const float*)d_in[0];
    const float* W = (const float*)d_in[1];
    const float* b = (const float*)d_in[2];
    const float* D = (const float*)d_in[3];
    float* out = (float*)d_out;
    float* recon = out;                                  // [8192*768]
    float* codes = out + (size_t)M * K;                  // [8192*16384]
    float* pre   = codes + (size_t)M * N;                // [8192*16384]

    hipLaunchKernelGGL(gemm_kernel, dim3((M / BM) * (N / BN)), dim3(256), 0, stream,
                       x, W, b, pre);
    hipLaunchKernelGGL(select_kernel, dim3(M), dim3(256), 0, stream,
                       pre, x, W, b, D, recon, codes);
}